// Round 6
// baseline (3267.678 us; speedup 1.0000x reference)
//
#include <hip/hip_runtime.h>
#include <stdint.h>

// DCRNN forward, MI355X — persistent dual-batch pipelined design.
//  - 256 blocks x 512 thr = 32 batch-PAIRS x 8 chunks; each block owns 32 rows
//    of TWO batches and alternates stage(b0)/stage(b1): each batch's barrier
//    propagation + L3 state-reload latency hides under the other batch's
//    compute. 8-block per-batch barrier; pair pinned to one XCD (blockIdx%8).
//  - 84992 B LDS forces 1 block/CU -> all 256 blocks co-resident (proven R3/R5).
//  - Cross-block state (H/RH/XD) via relaxed agent-scope atomics only (straight
//    to L3, placement-independent; no L2 wb/inv). A/Wp/bias normal cached loads.
//  - A = {S0, 2S0^2-I, S1, 2S1^2-I} bf16 (Chebyshev collapse) from prep.
//  - Per stage: xsT [f][n] staged in LDS; 4 hop GEMMs + 5-slice projection
//    (mfma_f32_16x16x32_bf16, fp32 accum); Hbuf double-buffered (4 syncs not 8);
//    h/u in MFMA-fragment registers across all 48 cells; fused GRU epilogue.

typedef short short8 __attribute__((ext_vector_type(8)));
typedef float f32x4 __attribute__((ext_vector_type(4)));
typedef unsigned short ushort4v __attribute__((ext_vector_type(4)));
typedef unsigned long long u64;
typedef u64 u64x2 __attribute__((ext_vector_type(2)));

#define DEVI __device__ __forceinline__

DEVI unsigned short f2bf(float x) {
  unsigned int u = __builtin_bit_cast(unsigned int, x);
  u += 0x7FFFu + ((u >> 16) & 1u);  // RNE
  return (unsigned short)(u >> 16);
}
DEVI u64 ald(const u64* p) { return __hip_atomic_load(p, __ATOMIC_RELAXED, __HIP_MEMORY_SCOPE_AGENT); }
DEVI void ast(u64* p, u64 v) { __hip_atomic_store(p, v, __ATOMIC_RELAXED, __HIP_MEMORY_SCOPE_AGENT); }
DEVI float aldf(const float* p) { return __hip_atomic_load(p, __ATOMIC_RELAXED, __HIP_MEMORY_SCOPE_AGENT); }
DEVI void astf(float* p, float v) { __hip_atomic_store(p, v, __ATOMIC_RELAXED, __HIP_MEMORY_SCOPE_AGENT); }

struct KP {
  const float* enc_in;
  const float* sup0; const float* sup1;
  const float* Wsrc[8];
  const float* bias[8];
  const float* prW; const float* prB;
  float* out;
  unsigned short* A;        // [4][256][256] bf16
  unsigned short* Wp[8];    // packed [O][5*FP] bf16
  unsigned short* H0[2];    // [64 b][64 f][256 n] bf16 rows, ping-pong
  unsigned short* H1[2];
  unsigned short* RH0;      // r*h rows
  unsigned short* RH1;
  float* XD;                // [64][256] decoder feedback
  unsigned* ctr;            // 64 per-batch counters, 256B apart
};

// ---------------- prep kernel (512 blocks x 256) ----------------
__global__ void prep(KP p) {
  const int i = blockIdx.x, tid = threadIdx.x;
  {  // A matrices
    const int s = i & 1, r = i >> 1;
    const float* S = s ? p.sup1 : p.sup0;
    float acc = 0.f;
    for (int k = 0; k < 256; ++k) acc = fmaf(S[r * 256 + k], S[k * 256 + tid], acc);
    p.A[(2 * s + 0) * 65536 + r * 256 + tid] = f2bf(S[r * 256 + tid]);
    p.A[(2 * s + 1) * 65536 + r * 256 + tid] = f2bf(2.f * acc - (r == tid ? 1.f : 0.f));
  }
  {  // packed weights: Wp[o][m*FP+f] = W[f,m,o], f zero-padded to FP
    const int gtid = i * 256 + tid;
    const int Fs[8]  = {66, 66, 128, 128, 65, 65, 128, 128};
    const int Os[8]  = {128, 64, 128, 64, 128, 64, 128, 64};
    const int FPs[8] = {96, 96, 128, 128, 96, 96, 128, 128};
    for (int w = 0; w < 8; ++w) {
      const int FPw = FPs[w], KPw = 5 * FPw, tot = Os[w] * KPw;
      for (int e = gtid; e < tot; e += 512 * 256) {
        const int o = e / KPw, k2 = e - o * KPw, m = k2 / FPw, f = k2 - m * FPw;
        p.Wp[w][e] = f2bf((f < Fs[w]) ? p.Wsrc[w][(f * 5 + m) * Os[w] + o] : 0.f);
      }
    }
  }
  {  // zero initial hidden via agent-scope stores
    const int gtid = i * 256 + tid;
    u64* z0 = (u64*)p.H0[0];
    u64* z1 = (u64*)p.H1[0];
    ast(z0 + 2 * gtid, 0); ast(z0 + 2 * gtid + 1, 0);
    ast(z1 + 2 * gtid, 0); ast(z1 + 2 * gtid + 1, 0);
  }
  if (i == 0 && tid < 64)
    __hip_atomic_store(p.ctr + tid * 64, 0u, __ATOMIC_RELAXED, __HIP_MEMORY_SCOPE_AGENT);
}

// ---------------- fused diffusion-conv stage (32 rows/block) ----------------
// MODE 0: gates (O=128, sigmoid; writes RH rows, u reg)
// MODE 1: cand  (O=64, tanh; GRU update of hreg; writes H rows)
// MODE 2: MODE1 + final projection (writes out slice and XD)
template<int IND, int FP, int MODE>
DEVI void dc_stage(int b, int n0, int tid,
                   const float* xf32,             // IND<=2 x input (IND==1 via sc1)
                   const unsigned short* xbf,     // IND==64 bf16 rows [64][256]
                   const unsigned short* hrows,   // bf16 rows [64][256] (h or r*h)
                   const unsigned short* Amats,
                   const unsigned short* Wp, const float* bias,
                   f32x4& hreg, f32x4& ureg,
                   unsigned short* grows,         // output rows (RH or Hnew)
                   const float* projW, const float* projB,
                   float* outp, float* xdout,
                   unsigned short* xsT, unsigned short* Hbuf)
{
  constexpr int F = IND + 64;
  constexpr int O = (MODE == 0) ? 128 : 64;
  constexpr int KPW = 5 * FP;
  constexpr int XS = 264;            // xsT row stride (bf16 elems)
  constexpr int HS = 136;            // Hbuf row stride
  constexpr int HB = 32 * HS;        // one Hbuf buffer (32 rows)
  constexpr int NFT = FP / 16;
  constexpr int NOT_ = O / 16;
  constexpr int FT_W = (NFT + 3) / 4;
  constexpr int OT_W = (NOT_ + 3) / 4;

  const int wv8 = tid >> 6, ln = tid & 63;
  const int l15 = ln & 15, l4 = ln >> 4;
  const int wr = wv8 & 1, wc = wv8 >> 1;   // 16-row tile / output-tile column group
  const int r0 = wr * 16;

  // ---- build xsT [f][n]: state rows via sc1 16B loads (all in flight) ----
  // 64 rows x 256 cols bf16 = 4096 u64; row = g>>5, c = g&31, dest col = c*8.
  {
    u64 la[4], lb[4];
    const u64* src = (const u64*)hrows;
#pragma unroll
    for (int it = 0; it < 4; ++it) { const int g = tid + it * 512; la[it] = ald(src + 2 * g); lb[it] = ald(src + 2 * g + 1); }
#pragma unroll
    for (int it = 0; it < 4; ++it) {
      const int g = tid + it * 512, row = g >> 5, c = g & 31;
      u64x2 v; v[0] = la[it]; v[1] = lb[it];
      *reinterpret_cast<u64x2*>(&xsT[(IND + row) * XS + c * 8]) = v;
    }
  }
  if (IND == 64) {
    u64 la[4], lb[4];
    const u64* src = (const u64*)xbf;
#pragma unroll
    for (int it = 0; it < 4; ++it) { const int g = tid + it * 512; la[it] = ald(src + 2 * g); lb[it] = ald(src + 2 * g + 1); }
#pragma unroll
    for (int it = 0; it < 4; ++it) {
      const int g = tid + it * 512, row = g >> 5, c = g & 31;
      u64x2 v; v[0] = la[it]; v[1] = lb[it];
      *reinterpret_cast<u64x2*>(&xsT[row * XS + c * 8]) = v;
    }
  } else if (IND == 2) {
    const float v = xf32[tid];               // read-only input, cached
    xsT[(tid & 1) * XS + (tid >> 1)] = f2bf(v);
  } else {  // IND == 1 (decoder feedback via sc1)
    if (tid < 256) xsT[tid] = xf32 ? f2bf(aldf(xf32 + tid)) : (unsigned short)0;
  }
  if (F < FP) {
    for (int e = tid; e < (FP - F) * 256; e += 512)
      xsT[(F + (e >> 8)) * XS + (e & 255)] = 0;
  }
  __syncthreads();
  // ---- Hbuf[0] = transpose of xsT columns [n0,n0+32): [nl][f] (pads included) ----
  for (int e = tid; e < FP * 32; e += 512) {
    const int f = e >> 5, nl = e & 31;
    Hbuf[nl * HS + f] = xsT[f * XS + n0 + nl];
  }
  __syncthreads();

  f32x4 pacc[OT_W];
#pragma unroll
  for (int oi = 0; oi < OT_W; ++oi) pacc[oi] = 0.f;

  auto proj_step = [&](int m, const unsigned short* hb) {
#pragma unroll
    for (int k0 = 0; k0 < FP; k0 += 32) {
      short8 af = *reinterpret_cast<const short8*>(&hb[(r0 + l15) * HS + k0 + l4 * 8]);
#pragma unroll
      for (int oi = 0; oi < OT_W; ++oi) {
        const int ot = wc + 4 * oi;
        if (ot < NOT_) {
          short8 bf = *reinterpret_cast<const short8*>(&Wp[(ot * 16 + l15) * KPW + m * FP + k0 + l4 * 8]);
          pacc[oi] = __builtin_amdgcn_mfma_f32_16x16x32_bf16(af, bf, pacc[oi], 0, 0, 0);
        }
      }
    }
  };

  proj_step(0, Hbuf);  // identity slice

  for (int mi = 0; mi < 4; ++mi) {
    const unsigned short* Am = Amats + mi * 65536;
    f32x4 hacc[FT_W];
#pragma unroll
    for (int fi = 0; fi < FT_W; ++fi) hacc[fi] = 0.f;

#pragma unroll
    for (int k0 = 0; k0 < 256; k0 += 32) {
      short8 af = *reinterpret_cast<const short8*>(&Am[(n0 + r0 + l15) * 256 + k0 + l4 * 8]);
#pragma unroll
      for (int fi = 0; fi < FT_W; ++fi) {
        const int ft = wc + 4 * fi;
        if (ft < NFT) {
          short8 bf = *reinterpret_cast<const short8*>(&xsT[(ft * 16 + l15) * XS + k0 + l4 * 8]);
          hacc[fi] = __builtin_amdgcn_mfma_f32_16x16x32_bf16(af, bf, hacc[fi], 0, 0, 0);
        }
      }
    }
    // double-buffered: write hop mi into buf[(mi+1)&1] while proj(mi) read buf[mi&1]
    unsigned short* dst = Hbuf + ((mi + 1) & 1) * HB;
#pragma unroll
    for (int fi = 0; fi < FT_W; ++fi) {
      const int ft = wc + 4 * fi;
      if (ft < NFT) {
#pragma unroll
        for (int j = 0; j < 4; ++j)
          dst[(r0 + l4 * 4 + j) * HS + ft * 16 + l15] = f2bf(hacc[fi][j]);
      }
    }
    __syncthreads();
    proj_step(mi + 1, dst);
  }

  // ---- epilogue ----
  if (MODE == 0) {
    const float br = bias[wc * 16 + l15];
    const float bu = bias[64 + wc * 16 + l15];
    f32x4 uu;
    ushort4v pk;
#pragma unroll
    for (int jj = 0; jj < 4; ++jj) {
      const float r = 1.f / (1.f + __expf(-(pacc[0][jj] + br)));
      uu[jj] = 1.f / (1.f + __expf(-(pacc[1][jj] + bu)));
      pk[jj] = f2bf(r * hreg[jj]);
    }
    ureg = uu;
    ast((u64*)(grows + (wc * 16 + l15) * 256 + n0 + r0 + l4 * 4),
        __builtin_bit_cast(u64, pk));
  } else {
    float* hrow = reinterpret_cast<float*>(Hbuf);   // [32][68] fp32 overlay of buf0
    if (MODE == 2) __syncthreads();                 // proj(4) readers (buf0) done
    const float bc = bias[wc * 16 + l15];
    f32x4 hn;
    ushort4v pk;
#pragma unroll
    for (int jj = 0; jj < 4; ++jj) {
      const float ex = __expf(2.f * (pacc[0][jj] + bc));
      const float c = 1.f - 2.f / (ex + 1.f);       // tanh
      hn[jj] = ureg[jj] * hreg[jj] + (1.f - ureg[jj]) * c;
      pk[jj] = f2bf(hn[jj]);
    }
    hreg = hn;
    ast((u64*)(grows + (wc * 16 + l15) * 256 + n0 + r0 + l4 * 4),
        __builtin_bit_cast(u64, pk));
    if (MODE == 2) {
#pragma unroll
      for (int jj = 0; jj < 4; ++jj)
        hrow[(r0 + l4 * 4 + jj) * 68 + wc * 16 + l15] = hn[jj];
      __syncthreads();
      if (tid < 32) {
        float acc = projB[0];
        const float* hr = hrow + tid * 68;
#pragma unroll
        for (int hid = 0; hid < 64; ++hid) acc = fmaf(hr[hid], projW[hid], acc);
        outp[b * 3072 + n0 + tid] = acc;            // normal store (host-read only)
        astf(xdout + b * 256 + n0 + tid, acc);      // sc1 (cross-block feedback)
      }
    }
  }
}

// ---------------- persistent main kernel (256 blocks x 512) ----------------
__launch_bounds__(512, 1)
__global__ void dcrnn_main(KP p) {
  __shared__ __align__(16) unsigned short xsT[128 * 264];     // 67584 B
  __shared__ __align__(16) unsigned short Hbuf[2 * 32 * 136]; // 17408 B -> 84992, 1 blk/CU
  const int tid = threadIdx.x;
  const int i = (int)blockIdx.x;
  const int xcd = i & 7, slot = i >> 3;        // 8 XCDs x 32 slots
  const int pr = xcd * 4 + (slot >> 3);        // batch pair 0..31 (8 blocks, one XCD)
  const int q = slot & 7;                      // row chunk 0..7
  const int b0 = 2 * pr, b1 = b0 + 1;
  const int n0 = q * 32;

  unsigned* ctr0 = p.ctr + b0 * 64;
  unsigned* ctr1 = p.ctr + b1 * 64;
  unsigned st = 0;

  auto ARRIVEB = [&](unsigned* c) {
    asm volatile("s_waitcnt vmcnt(0)" ::: "memory");  // state stores (sc1) at L3
    __syncthreads();
    if (tid == 0) __hip_atomic_fetch_add(c, 1u, __ATOMIC_RELAXED, __HIP_MEMORY_SCOPE_AGENT);
  };
  auto WAITB = [&](unsigned* c, unsigned target) {
    if (tid == 0) {
      while (__hip_atomic_load(c, __ATOMIC_RELAXED, __HIP_MEMORY_SCOPE_AGENT) < target)
        __builtin_amdgcn_s_sleep(1);
    }
    __syncthreads();
  };

#define DO_PAIR(CALL0, CALL1)                          \
  {                                                    \
    if (st) WAITB(ctr0, st * 8u);                      \
    CALL0; ARRIVEB(ctr0);                              \
    if (st) WAITB(ctr1, st * 8u);                      \
    CALL1; ARRIVEB(ctr1);                              \
    ++st;                                              \
  }

  f32x4 h0a, h1a, ua, h0b, h1b, ub;
  h0a = 0.f; h1a = 0.f; ua = 0.f; h0b = 0.f; h1b = 0.f; ub = 0.f;
  int c0 = 0, c1 = 0;

  // ---- encoder ----
  for (int t = 0; t < 12; ++t) {
    const float* xa = p.enc_in + (b0 * 12 + t) * 512;
    const float* xb = p.enc_in + (b1 * 12 + t) * 512;
    DO_PAIR(
      (dc_stage<2, 96, 0>(b0, n0, tid, xa, nullptr, p.H0[c0] + b0 * 16384, p.A, p.Wp[0], p.bias[0],
                          h0a, ua, p.RH0 + b0 * 16384, nullptr, nullptr, nullptr, nullptr, xsT, Hbuf)),
      (dc_stage<2, 96, 0>(b1, n0, tid, xb, nullptr, p.H0[c0] + b1 * 16384, p.A, p.Wp[0], p.bias[0],
                          h0b, ub, p.RH0 + b1 * 16384, nullptr, nullptr, nullptr, nullptr, xsT, Hbuf)));
    DO_PAIR(
      (dc_stage<2, 96, 1>(b0, n0, tid, xa, nullptr, p.RH0 + b0 * 16384, p.A, p.Wp[1], p.bias[1],
                          h0a, ua, p.H0[c0 ^ 1] + b0 * 16384, nullptr, nullptr, nullptr, nullptr, xsT, Hbuf)),
      (dc_stage<2, 96, 1>(b1, n0, tid, xb, nullptr, p.RH0 + b1 * 16384, p.A, p.Wp[1], p.bias[1],
                          h0b, ub, p.H0[c0 ^ 1] + b1 * 16384, nullptr, nullptr, nullptr, nullptr, xsT, Hbuf)));
    c0 ^= 1;
    DO_PAIR(
      (dc_stage<64, 128, 0>(b0, n0, tid, nullptr, p.H0[c0] + b0 * 16384, p.H1[c1] + b0 * 16384, p.A, p.Wp[2], p.bias[2],
                            h1a, ua, p.RH1 + b0 * 16384, nullptr, nullptr, nullptr, nullptr, xsT, Hbuf)),
      (dc_stage<64, 128, 0>(b1, n0, tid, nullptr, p.H0[c0] + b1 * 16384, p.H1[c1] + b1 * 16384, p.A, p.Wp[2], p.bias[2],
                            h1b, ub, p.RH1 + b1 * 16384, nullptr, nullptr, nullptr, nullptr, xsT, Hbuf)));
    DO_PAIR(
      (dc_stage<64, 128, 1>(b0, n0, tid, nullptr, p.H0[c0] + b0 * 16384, p.RH1 + b0 * 16384, p.A, p.Wp[3], p.bias[3],
                            h1a, ua, p.H1[c1 ^ 1] + b0 * 16384, nullptr, nullptr, nullptr, nullptr, xsT, Hbuf)),
      (dc_stage<64, 128, 1>(b1, n0, tid, nullptr, p.H0[c0] + b1 * 16384, p.RH1 + b1 * 16384, p.A, p.Wp[3], p.bias[3],
                            h1b, ub, p.H1[c1 ^ 1] + b1 * 16384, nullptr, nullptr, nullptr, nullptr, xsT, Hbuf)));
    c1 ^= 1;
  }

  // ---- decoder ----
  for (int t = 0; t < 12; ++t) {
    const float* xda = t ? (p.XD + b0 * 256) : nullptr;
    const float* xdb = t ? (p.XD + b1 * 256) : nullptr;
    DO_PAIR(
      (dc_stage<1, 96, 0>(b0, n0, tid, xda, nullptr, p.H0[c0] + b0 * 16384, p.A, p.Wp[4], p.bias[4],
                          h0a, ua, p.RH0 + b0 * 16384, nullptr, nullptr, nullptr, nullptr, xsT, Hbuf)),
      (dc_stage<1, 96, 0>(b1, n0, tid, xdb, nullptr, p.H0[c0] + b1 * 16384, p.A, p.Wp[4], p.bias[4],
                          h0b, ub, p.RH0 + b1 * 16384, nullptr, nullptr, nullptr, nullptr, xsT, Hbuf)));
    DO_PAIR(
      (dc_stage<1, 96, 1>(b0, n0, tid, xda, nullptr, p.RH0 + b0 * 16384, p.A, p.Wp[5], p.bias[5],
                          h0a, ua, p.H0[c0 ^ 1] + b0 * 16384, nullptr, nullptr, nullptr, nullptr, xsT, Hbuf)),
      (dc_stage<1, 96, 1>(b1, n0, tid, xdb, nullptr, p.RH0 + b1 * 16384, p.A, p.Wp[5], p.bias[5],
                          h0b, ub, p.H0[c0 ^ 1] + b1 * 16384, nullptr, nullptr, nullptr, nullptr, xsT, Hbuf)));
    c0 ^= 1;
    DO_PAIR(
      (dc_stage<64, 128, 0>(b0, n0, tid, nullptr, p.H0[c0] + b0 * 16384, p.H1[c1] + b0 * 16384, p.A, p.Wp[6], p.bias[6],
                            h1a, ua, p.RH1 + b0 * 16384, nullptr, nullptr, nullptr, nullptr, xsT, Hbuf)),
      (dc_stage<64, 128, 0>(b1, n0, tid, nullptr, p.H0[c0] + b1 * 16384, p.H1[c1] + b1 * 16384, p.A, p.Wp[6], p.bias[6],
                            h1b, ub, p.RH1 + b1 * 16384, nullptr, nullptr, nullptr, nullptr, xsT, Hbuf)));
    DO_PAIR(
      (dc_stage<64, 128, 2>(b0, n0, tid, nullptr, p.H0[c0] + b0 * 16384, p.RH1 + b0 * 16384, p.A, p.Wp[7], p.bias[7],
                            h1a, ua, p.H1[c1 ^ 1] + b0 * 16384, p.prW, p.prB, p.out + t * 256, p.XD, xsT, Hbuf)),
      (dc_stage<64, 128, 2>(b1, n0, tid, nullptr, p.H0[c0] + b1 * 16384, p.RH1 + b1 * 16384, p.A, p.Wp[7], p.bias[7],
                            h1b, ub, p.H1[c1 ^ 1] + b1 * 16384, p.prW, p.prB, p.out + t * 256, p.XD, xsT, Hbuf)));
    c1 ^= 1;
  }
#undef DO_PAIR
}

// ---------------- host ----------------
extern "C" void kernel_launch(void* const* d_in, const int* in_sizes, int n_in,
                              void* d_out, int out_size, void* d_ws, size_t ws_size,
                              hipStream_t stream)
{
  (void)in_sizes; (void)n_in; (void)out_size; (void)ws_size;
  KP p;
  p.enc_in = (const float*)d_in[0];
  p.sup0 = (const float*)d_in[2];
  p.sup1 = (const float*)d_in[3];
  p.Wsrc[0] = (const float*)d_in[4];  p.bias[0] = (const float*)d_in[5];
  p.Wsrc[1] = (const float*)d_in[6];  p.bias[1] = (const float*)d_in[7];
  p.Wsrc[2] = (const float*)d_in[8];  p.bias[2] = (const float*)d_in[9];
  p.Wsrc[3] = (const float*)d_in[10]; p.bias[3] = (const float*)d_in[11];
  p.Wsrc[4] = (const float*)d_in[12]; p.bias[4] = (const float*)d_in[13];
  p.Wsrc[5] = (const float*)d_in[14]; p.bias[5] = (const float*)d_in[15];
  p.Wsrc[6] = (const float*)d_in[16]; p.bias[6] = (const float*)d_in[17];
  p.Wsrc[7] = (const float*)d_in[18]; p.bias[7] = (const float*)d_in[19];
  p.prW = (const float*)d_in[20];
  p.prB = (const float*)d_in[21];
  p.out = (float*)d_out;

  char* ws = (char*)d_ws;
  size_t off = 0;
  auto carve = [&](size_t bytes) -> char* {
    char* qp = ws + off;
    off += (bytes + 255) & ~(size_t)255;
    return qp;
  };
  p.A = (unsigned short*)carve(4 * 65536 * 2);
  p.Wp[0] = (unsigned short*)carve(128 * 480 * 2);
  p.Wp[1] = (unsigned short*)carve(64 * 480 * 2);
  p.Wp[2] = (unsigned short*)carve(128 * 640 * 2);
  p.Wp[3] = (unsigned short*)carve(64 * 640 * 2);
  p.Wp[4] = (unsigned short*)carve(128 * 480 * 2);
  p.Wp[5] = (unsigned short*)carve(64 * 480 * 2);
  p.Wp[6] = (unsigned short*)carve(128 * 640 * 2);
  p.Wp[7] = (unsigned short*)carve(64 * 640 * 2);
  p.H0[0] = (unsigned short*)carve(64 * 64 * 256 * 2);
  p.H0[1] = (unsigned short*)carve(64 * 64 * 256 * 2);
  p.H1[0] = (unsigned short*)carve(64 * 64 * 256 * 2);
  p.H1[1] = (unsigned short*)carve(64 * 64 * 256 * 2);
  p.RH0 = (unsigned short*)carve(64 * 64 * 256 * 2);
  p.RH1 = (unsigned short*)carve(64 * 64 * 256 * 2);
  p.XD = (float*)carve(64 * 256 * 4);
  p.ctr = (unsigned*)carve(64 * 256);

  prep<<<dim3(512), dim3(256), 0, stream>>>(p);
  dcrnn_main<<<dim3(256), dim3(512), 0, stream>>>(p);
}